// Round 2
// 235.863 us; speedup vs baseline: 1.0370x; 1.0370x over previous
//
#include <hip/hip_runtime.h>

typedef __attribute__((ext_vector_type(8))) __bf16 bf16x8;
typedef __attribute__((ext_vector_type(4))) float f32x4;

constexpr int Bsz   = 128;
constexpr int EE    = 200;
constexpr int EP    = 256;   // padded embed dim
constexpr int KP    = 224;   // padded K loop bound for gemm2/3 (covers 200)
constexpr int NN    = 256;
constexpr int NMASK = 192;
constexpr int NVIS  = 64;
constexpr int PE    = 768;
constexpr int M1    = Bsz * NVIS;   // 8192
constexpr int M3    = M1 + NMASK;   // 8384
constexpr long IMG_ELEMS = (long)Bsz * 3 * 256 * 256;

constexpr int VBLK = 256;    // visible mega-blocks (32 rows each)
constexpr int ASTR = 776;    // As LDS stride in bf16 elems (768+8: bank-stride 4 mod 32)
constexpr int TSTR = 264;    // visible/full tile LDS stride (256+8)
constexpr int FOFF = 32 * TSTR;   // ful_t offset inside smem (aliases dead As upper half)

__device__ __forceinline__ f32x4 mfma16(bf16x8 a, bf16x8 b, f32x4 c) {
    return __builtin_amdgcn_mfma_f32_16x16x32_bf16(a, b, c, 0, 0, 0);
}

// ---------------------------------------------------------------------------
// Prep: pad/convert weights to bf16 (B matrices in n-major [n][k] layout),
// pad pos/biases, write masked rows of `full`, emit masked_idx output.
// (unchanged from verified baseline)
// ---------------------------------------------------------------------------
__global__ __launch_bounds__(256) void k_prep(
    const float* __restrict__ pos, const float* __restrict__ wflat,
    const float* __restrict__ Wenc, const float* __restrict__ Wdec,
    const float* __restrict__ conv_b, const float* __restrict__ b_enc,
    const float* __restrict__ mask_token, const int* __restrict__ perm,
    float* __restrict__ posP, __bf16* __restrict__ W1t,
    __bf16* __restrict__ W2t, __bf16* __restrict__ W3t,
    float* __restrict__ cbp, float* __restrict__ bep,
    __bf16* __restrict__ full, float* __restrict__ out_idx)
{
    int blk = blockIdx.x, t = threadIdx.x;
    if (blk < 256) {                       // posP [256][256]
        posP[blk * 256 + t] = (t < EE) ? pos[blk * EE + t] : 0.f;
        return;
    }
    blk -= 256;
    if (blk < 768) {                       // W1t [256][768] = wflat padded (already n-major)
        int e = blk / 3, k = (blk % 3) * 256 + t;
        W1t[e * 768 + k] = (e < EE) ? (__bf16)wflat[e * 768 + k] : (__bf16)0.f;
        return;
    }
    blk -= 768;
    if (blk < 256) {                       // W2t [256][224] = Wenc^T padded
        if (t < KP) W2t[blk * KP + t] =
            (blk < EE && t < EE) ? (__bf16)Wenc[t * EE + blk] : (__bf16)0.f;
        return;
    }
    blk -= 256;
    if (blk < 768) {                       // W3t [768][224] = Wdec^T padded
        if (t < KP) W3t[blk * KP + t] =
            (t < EE) ? (__bf16)Wdec[t * PE + blk] : (__bf16)0.f;
        return;
    }
    blk -= 768;
    if (blk < NMASK) {                     // masked rows of full: mask_token + pos
        int n = perm[blk];
        full[(M1 + blk) * EP + t] =
            (t < EE) ? (__bf16)(mask_token[t] + pos[n * EE + t]) : (__bf16)0.f;
        return;
    }
    // final block: padded biases + masked_idx output
    cbp[t] = (t < EE) ? conv_b[t] : 0.f;
    bep[t] = (t < EE) ? b_enc[t] : 0.f;
    if (t < NMASK) out_idx[t] = (float)perm[t];
}

// ---------------------------------------------------------------------------
// Mega kernel: per 32-row m-tile, chain GEMM1 -> GEMM2 -> GEMM3 through LDS.
//   blocks [0, 256):  visible rows. phase0 stage A from x (f32->bf16);
//                     phase1 K=768 -> vis_t (LDS, aliases As[0:8448));
//                     phase2 K=224 -> ful_t (LDS, aliases As[8448:16896));
//                     phase3 K=224 -> img stores.
//   blocks [256,262): masked rows (batch-independent): full -> dec_masked.
// B fragments are read straight from global (weights are L2-resident, 832 KB
// total) with loop-invariant addresses + immediate k0 offsets, so every
// K-loop is barrier-free. 4 __syncthreads total for the visible path.
// LDS total = 32*ASTR*2 = 49664 B (< 64 KiB static limit).
// ---------------------------------------------------------------------------
__global__ __launch_bounds__(512) void k_mega(
    const float* __restrict__ x, const __bf16* __restrict__ W1t,
    const __bf16* __restrict__ W2t, const __bf16* __restrict__ W3t,
    const float* __restrict__ cbp, const float* __restrict__ bep,
    const float* __restrict__ posP, const float* __restrict__ bdec,
    const int* __restrict__ perm, const __bf16* __restrict__ fullg,
    float* __restrict__ img, float* __restrict__ dec_masked)
{
    __shared__ __bf16 smem[32 * ASTR];     // 49664 B
    __bf16* As    = smem;                  // stride ASTR (phase 0/1)
    __bf16* vis_t = smem;                  // stride TSTR, elems [0, 8448)
    __bf16* ful_t = smem + FOFF;           // stride TSTR, elems [8448, 16896)
    __shared__ int nidx[32];

    const int t    = threadIdx.x;
    const int bid  = blockIdx.x;
    const int lane = t & 63, wid = t >> 6;        // 8 waves
    const int quad = lane >> 4, lid = lane & 15;

    if (bid >= VBLK) {
        // ---------------- masked path: dec of full[8192 + mb*32 ..] ----------
        const int mb = bid - VBLK;
        #pragma unroll
        for (int it = 0; it < 2; ++it) {
            int cchunk = t + it * 512;            // [0,1024): 32 rows x 32 chunks
            int row = cchunk >> 5, col = (cchunk & 31) * 8;
            *(int4*)&ful_t[row * TSTR + col] =
                *(const int4*)&fullg[(M1 + mb * 32 + row) * EP + col];
        }
        __syncthreads();
        f32x4 acc[2][6] = {};
        const int p0w = wid * 96;
        for (int k0 = 0; k0 < KP; k0 += 32) {
            bf16x8 a0 = *(const bf16x8*)&ful_t[lid * TSTR + k0 + quad * 8];
            bf16x8 a1 = *(const bf16x8*)&ful_t[(16 + lid) * TSTR + k0 + quad * 8];
            #pragma unroll
            for (int j = 0; j < 6; ++j) {
                bf16x8 bv = *(const bf16x8*)&W3t[(p0w + j * 16 + lid) * KP + k0 + quad * 8];
                acc[0][j] = mfma16(a0, bv, acc[0][j]);
                acc[1][j] = mfma16(a1, bv, acc[1][j]);
            }
        }
        #pragma unroll
        for (int j = 0; j < 6; ++j) {
            const int p = p0w + j * 16 + lid;
            const float bd = bdec[p];
            #pragma unroll
            for (int i = 0; i < 2; ++i) {
                const int r0 = mb * 32 + i * 16 + quad * 4;
                #pragma unroll
                for (int r = 0; r < 4; ++r)
                    dec_masked[(r0 + r) * PE + p] = acc[i][j][r] + bd;
            }
        }
        return;
    }

    // ---------------- visible path ----------------
    const int m0 = bid * 32;
    if (t < 32) nidx[t] = perm[NMASK + (m0 & 63) + t];

    // phase 0: stage A tile (32 x 768) from x, f32 -> bf16, into As
    {
        const int row = t >> 4;
        const int m = m0 + row;
        const int n = perm[NMASK + (m & 63)];
        const int abase = (m >> 6) * 196608 + (n >> 4) * 4096 + (n & 15) * 16;
        #pragma unroll
        for (int it = 0; it < 6; ++it) {
            int k = (t & 15) * 8 + it * 128;
            int c = k >> 8, py = (k >> 4) & 15, px = k & 15;
            const float* ap = x + abase + c * 65536 + py * 256 + px;
            float4 a0 = *(const float4*)ap;
            float4 a1 = *(const float4*)(ap + 4);
            bf16x8 av;
            av[0] = (__bf16)a0.x; av[1] = (__bf16)a0.y; av[2] = (__bf16)a0.z; av[3] = (__bf16)a0.w;
            av[4] = (__bf16)a1.x; av[5] = (__bf16)a1.y; av[6] = (__bf16)a1.z; av[7] = (__bf16)a1.w;
            *(bf16x8*)&As[row * ASTR + k] = av;
        }
    }
    __syncthreads();

    // phase 1: 32x256 = A(32x768) . W1t^T, barrier-free K-loop
    const int e0w = wid * 32;
    f32x4 acc1[2][2] = {};
    for (int k0 = 0; k0 < 768; k0 += 32) {
        bf16x8 a0 = *(const bf16x8*)&As[lid * ASTR + k0 + quad * 8];
        bf16x8 a1 = *(const bf16x8*)&As[(16 + lid) * ASTR + k0 + quad * 8];
        #pragma unroll
        for (int j = 0; j < 2; ++j) {
            bf16x8 bv = *(const bf16x8*)&W1t[(e0w + j * 16 + lid) * 768 + k0 + quad * 8];
            acc1[0][j] = mfma16(a0, bv, acc1[0][j]);
            acc1[1][j] = mfma16(a1, bv, acc1[1][j]);
        }
    }
    __syncthreads();   // all waves done reading As before vis_t/ful_t overwrite it

    // epilogue 1: vis_t[m][e] = acc + cb[e] + pos[n][e]  (bf16)
    #pragma unroll
    for (int i = 0; i < 2; ++i) {
        const int mloc = i * 16 + quad * 4;
        #pragma unroll
        for (int j = 0; j < 2; ++j) {
            const int e = e0w + j * 16 + lid;
            const float cb = cbp[e];
            #pragma unroll
            for (int r = 0; r < 4; ++r) {
                const int ml = mloc + r;
                vis_t[ml * TSTR + e] =
                    (__bf16)(acc1[i][j][r] + cb + posP[nidx[ml] * 256 + e]);
            }
        }
    }
    __syncthreads();

    // phase 2: 32x256 = vis(32x224) . W2t^T, barrier-free K-loop
    f32x4 acc2[2][2] = {};
    for (int k0 = 0; k0 < KP; k0 += 32) {
        bf16x8 a0 = *(const bf16x8*)&vis_t[lid * TSTR + k0 + quad * 8];
        bf16x8 a1 = *(const bf16x8*)&vis_t[(16 + lid) * TSTR + k0 + quad * 8];
        #pragma unroll
        for (int j = 0; j < 2; ++j) {
            bf16x8 bv = *(const bf16x8*)&W2t[(e0w + j * 16 + lid) * KP + k0 + quad * 8];
            acc2[0][j] = mfma16(a0, bv, acc2[0][j]);
            acc2[1][j] = mfma16(a1, bv, acc2[1][j]);
        }
    }
    // epilogue 2: ful_t[m][f] = acc + be[f] + pos[n][f]  (disjoint LDS range,
    // so no barrier needed before writing; barrier after, before phase 3 reads)
    #pragma unroll
    for (int i = 0; i < 2; ++i) {
        const int mloc = i * 16 + quad * 4;
        #pragma unroll
        for (int j = 0; j < 2; ++j) {
            const int e = e0w + j * 16 + lid;
            const float be = bep[e];
            #pragma unroll
            for (int r = 0; r < 4; ++r) {
                const int ml = mloc + r;
                ful_t[ml * TSTR + e] =
                    (__bf16)(acc2[i][j][r] + be + posP[nidx[ml] * 256 + e]);
            }
        }
    }
    __syncthreads();

    // phase 3: 32x768 = ful(32x224) . W3t^T, barrier-free K-loop; store to img
    f32x4 acc3[2][6] = {};
    const int p0w = wid * 96;
    for (int k0 = 0; k0 < KP; k0 += 32) {
        bf16x8 a0 = *(const bf16x8*)&ful_t[lid * TSTR + k0 + quad * 8];
        bf16x8 a1 = *(const bf16x8*)&ful_t[(16 + lid) * TSTR + k0 + quad * 8];
        #pragma unroll
        for (int j = 0; j < 6; ++j) {
            bf16x8 bv = *(const bf16x8*)&W3t[(p0w + j * 16 + lid) * KP + k0 + quad * 8];
            acc3[0][j] = mfma16(a0, bv, acc3[0][j]);
            acc3[1][j] = mfma16(a1, bv, acc3[1][j]);
        }
    }
    const int bimg = m0 >> 6;
    #pragma unroll
    for (int j = 0; j < 6; ++j) {
        const int p = p0w + j * 16 + lid;
        const int c = p >> 8, py = (p >> 4) & 15, px = p & 15;
        const float bd = bdec[p];
        const long obase = (long)(bimg * 3 + c) * 65536 + py * 256 + px;
        #pragma unroll
        for (int i = 0; i < 2; ++i) {
            const int mloc = i * 16 + quad * 4;
            #pragma unroll
            for (int r = 0; r < 4; ++r) {
                const int n = nidx[mloc + r];
                img[obase + (n >> 4) * 4096 + (n & 15) * 16] = acc3[i][j][r] + bd;
            }
        }
    }
}

// ---------------------------------------------------------------------------
// Broadcast masked decoder rows (batch-independent) to all images.
// Block = one masked patch x 8 batches: read patch once, store 8x.
// ---------------------------------------------------------------------------
__global__ __launch_bounds__(192) void k_foldmask(
    const float* __restrict__ dec_masked, const int* __restrict__ perm,
    float* __restrict__ img)
{
    const int i  = blockIdx.x;        // masked patch slot 0..191
    const int b0 = blockIdx.y * 8;    // batch group
    const int n  = perm[i];
    const int t  = threadIdx.x;
    float4 v = *(const float4*)&dec_masked[i * PE + t * 4];
    int p = t * 4;
    int c = p >> 8, py = (p >> 4) & 15, px = p & 15;
    const long base = (long)c * 65536 + (n >> 4) * 4096 + (n & 15) * 16 + py * 256 + px;
    #pragma unroll
    for (int bb = 0; bb < 8; ++bb)
        *(float4*)&img[(long)(b0 + bb) * 3 * 65536 + base] = v;
}

// ---------------------------------------------------------------------------
extern "C" void kernel_launch(void* const* d_in, const int* in_sizes, int n_in,
                              void* d_out, int out_size, void* d_ws, size_t ws_size,
                              hipStream_t stream)
{
    const float* x          = (const float*)d_in[0];
    const float* conv_w     = (const float*)d_in[1];
    const float* conv_b     = (const float*)d_in[2];
    const float* pos        = (const float*)d_in[3];
    const float* mask_token = (const float*)d_in[4];
    const float* W_enc      = (const float*)d_in[5];
    const float* b_enc      = (const float*)d_in[6];
    const float* W_dec      = (const float*)d_in[7];
    const float* b_dec      = (const float*)d_in[8];
    const int*   perm       = (const int*)d_in[9];
    float* out = (float*)d_out;

    // workspace carve-up (all offsets 16B-aligned; layout kept from baseline)
    __bf16* visible = (__bf16*)d_ws;                    // (unused now)
    __bf16* full    = visible + M1 * EP;                // masked rows used
    __bf16* W1t     = full + M3 * EP;                   // 256*768
    __bf16* W2t     = W1t + 256 * 768;                  // 256*224
    __bf16* W3t     = W2t + 256 * KP;                   // 768*224
    float*  posP    = (float*)(W3t + 768 * KP);         // 256*256
    float*  cbp     = posP + 256 * 256;                 // 256
    float*  bep     = cbp + 256;                        // 256
    float*  decm    = bep + 256;                        // 192*768

    k_prep<<<256 + 768 + 256 + 768 + NMASK + 1, 256, 0, stream>>>(
        pos, conv_w, W_enc, W_dec, conv_b, b_enc, mask_token, perm,
        posP, W1t, W2t, W3t, cbp, bep, full, out + IMG_ELEMS);
    k_mega<<<VBLK + NMASK / 32, 512, 0, stream>>>(
        x, W1t, W2t, W3t, cbp, bep, posP, b_dec, perm, full, out, decm);
    k_foldmask<<<dim3(NMASK, Bsz / 8), 192, 0, stream>>>(decm, perm, out);
}